// Round 22
// baseline (108.684 us; speedup 1.0000x reference)
//
#include <hip/hip_runtime.h>
#include <hip/hip_bf16.h>

// IDWT2D db4, periodized. Input x: [64][256][256][16] f32 (cA|cH|cV|cD x 4ch),
// output: [64][512][512][4] f32.
//
// R21 = R20 with the prefetch off-by-two FIXED: chunk c's tail must load
// rows 2c+8, 2c+9 (consumed by chunk c+1's slides of rows 2(c+1)+6/+7),
// not 2c+6/2c+7 (already consumed this chunk). R20's bug left every slid
// row stale by 2 and never loaded row 18 -> absmax 8.45.
// Structure: 2-row chunks (8 barriers/block vs 16), bf16-packed LDS
// intermediate (33 KB, accuracy proven in R11: absmax 0.031 <= 0.115),
// dense lane-contiguous pass1 loads (thread t owns f4 cols t, t+512),
// lane-pair partial exchange via __shfl_xor, plane layout
// (0=lo*p0,1=lo*p1,2=hi*p0,3=hi*p1), pass2 thread = output column
// (dense f4 stores), lgkm-only barrier, pk-fma.

#define N 256
#define RJ 16
#define NC (RJ / 2)

typedef float f32x4 __attribute__((ext_vector_type(4)));

// lgkm-only barrier: LDS producer-consumer sync without vmcnt drain.
#define LGKM_BARRIER()                                   \
  do {                                                   \
    asm volatile("s_waitcnt lgkmcnt(0)" ::: "memory");   \
    __builtin_amdgcn_s_barrier();                        \
    asm volatile("" ::: "memory");                       \
  } while (0)

__device__ __forceinline__ f32x4 fma4v(const f32x4 acc, const float s,
                                       const f32x4 a) {
  const f32x4 sv = {s, s, s, s};
  return __builtin_elementwise_fma(a, sv, acc);
}

__device__ __forceinline__ f32x4 shflxor1(const f32x4 v) {
  f32x4 r;
  r.x = __shfl_xor(v.x, 1);
  r.y = __shfl_xor(v.y, 1);
  r.z = __shfl_xor(v.z, 1);
  r.w = __shfl_xor(v.w, 1);
  return r;
}

__device__ __forceinline__ uint2 pack_bf16x4(const f32x4 v) {
  __hip_bfloat162 lo = __float22bfloat162_rn(make_float2(v.x, v.y));
  __hip_bfloat162 hi = __float22bfloat162_rn(make_float2(v.z, v.w));
  uint2 r;
  r.x = *reinterpret_cast<const unsigned int*>(&lo);
  r.y = *reinterpret_cast<const unsigned int*>(&hi);
  return r;
}

__device__ __forceinline__ f32x4 unpack_bf16x4(const uint2 u) {
  f32x4 r;
  r.x = __uint_as_float(u.x << 16);
  r.y = __uint_as_float(u.x & 0xffff0000u);
  r.z = __uint_as_float(u.y << 16);
  r.w = __uint_as_float(u.y & 0xffff0000u);
  return r;
}

__global__ __launch_bounds__(512, 4) void idwt2_sep21_kernel(
    const float* __restrict__ x, float* __restrict__ out) {
  constexpr float LO[8] = {
      0.23037781330885523f,  0.7148465705525415f,  0.6308807679295904f,
      -0.02798376941698385f, -0.18703481171888114f, 0.030841381835986965f,
      0.032883011666982945f, -0.010597401784997278f};
  constexpr float HIW[8] = {
      -0.010597401784997278f, -0.032883011666982945f, 0.030841381835986965f,
      0.18703481171888114f,  -0.02798376941698385f,  -0.6308807679295904f,
      0.7148465705525415f,   -0.23037781330885523f};
  const float Lw[2][4] = {{LO[6], LO[4], LO[2], LO[0]},
                          {LO[7], LO[5], LO[3], LO[1]}};
  const float Hw[2][4] = {{HIW[6], HIW[4], HIW[2], HIW[0]},
                          {HIW[7], HIW[5], HIW[3], HIW[1]}};

  // [chunk-buf][row-in-chunk][plane][pixel] bf16x4, padded 256->258.
  __shared__ uint2 I[2][2][4][258];  // 33 KB

  const int t = threadIdx.x;
  const int bx = blockIdx.x;
  const int b = bx >> 4;           // 16 consecutive blocks per batch
  const int r0 = (bx & 15) * RJ;

  const f32x4* xb = reinterpret_cast<const f32x4*>(x) + (size_t)b * N * N * 4;
  f32x4* ob = reinterpret_cast<f32x4*>(out) + (size_t)b * (2 * N) * (2 * N);

  // ---- Pass1 identity: f4 index j = t (pixel p, subband-f4 f) + j+512 ----
  const int f = t & 3;
  const int p = t >> 2;  // 0..127; second column is p+128
  const bool fo = f & 1; // false: cA/cV (Lw family), true: cH/cD (Hw family)

  float w_own[4], w_opp[4];  // own-parity / opposite-parity weights
#pragma unroll
  for (int s = 0; s < 4; ++s) {
    w_own[s] = fo ? Hw[1][s] : Lw[0][s];
    w_opp[s] = fo ? Hw[0][s] : Lw[1][s];
  }

  f32x4 w0[4], w1[4];        // sliding windows for columns t, t+512
  f32x4 nA0, nB0, nA1, nB1;  // 2-row prefetch: rows 2c+6, 2c+7 at chunk c
  auto ldrow = [&](int lr, f32x4& A, f32x4& B) {
    const int gr = (r0 + lr) & (N - 1);
    const f32x4* xrow = xb + (size_t)gr * (N * 4);
    A = xrow[t];
    B = xrow[t + 512];
  };

  // y-filter local j-row j into I[buf][r]; window slot (j+sy)&3 = row j+sy.
  auto p1 = [&](int j, int buf, int r) {
    f32x4 sAo = {0.f, 0.f, 0.f, 0.f}, sAx = {0.f, 0.f, 0.f, 0.f};
    f32x4 sBo = {0.f, 0.f, 0.f, 0.f}, sBx = {0.f, 0.f, 0.f, 0.f};
#pragma unroll
    for (int sy = 0; sy < 4; ++sy) {
      const f32x4 a = w0[(j + sy) & 3];
      const f32x4 bb = w1[(j + sy) & 3];
      sAo = fma4v(sAo, w_own[sy], a);
      sAx = fma4v(sAx, w_opp[sy], a);
      sBo = fma4v(sBo, w_own[sy], bb);
      sBx = fma4v(sBx, w_opp[sy], bb);
    }
    const f32x4 vA = sAo + shflxor1(sAx);
    const f32x4 vB = sBo + shflxor1(sBx);
    I[buf][r][f][p] = pack_bf16x4(vA);
    I[buf][r][f][p + 128] = pack_bf16x4(vB);
  };

  // Prologue: window rows 0..3; chunk 0 (rows 0,1) -> buf 0; rows 4,5 slide
  // in; prefetch rows 6,7 (consumed by chunk c=0's slides in the main loop).
#pragma unroll
  for (int m = 0; m < 4; ++m) ldrow(m, w0[m], w1[m]);
  ldrow(4, nA0, nB0);
  ldrow(5, nA1, nB1);
  p1(0, 0, 0);
  w0[0] = nA0;  // row 4 -> slot 0
  w1[0] = nB0;
  p1(1, 0, 1);
  w0[1] = nA1;  // row 5 -> slot 1
  w1[1] = nB1;
  ldrow(6, nA0, nB0);
  ldrow(7, nA1, nB1);
  LGKM_BARRIER();

  // ---- Pass2 identity: output column t (dense stores) ----
  const int jx = t >> 1;
  const int q = t & 1;
  float Lq[4], Hq[4];
#pragma unroll
  for (int s = 0; s < 4; ++s) {
    Lq[s] = q ? Lw[1][s] : Lw[0][s];
    Hq[s] = q ? Hw[1][s] : Hw[0][s];
  }

#pragma unroll
  for (int c = 0; c < NC; ++c) {
    const int buf = c & 1;

    // ---- Pass2: x-filter j-rows 2c, 2c+1 from I[buf] ----
#pragma unroll
    for (int r = 0; r < 2; ++r) {
      f32x4 o0 = {0.f, 0.f, 0.f, 0.f};
      f32x4 o1 = {0.f, 0.f, 0.f, 0.f};
#pragma unroll
      for (int s = 0; s < 4; ++s) {
        const int xc = (jx + s) & (N - 1);
        o0 = fma4v(o0, Lq[s], unpack_bf16x4(I[buf][r][0][xc]));
        o0 = fma4v(o0, Hq[s], unpack_bf16x4(I[buf][r][2][xc]));
        o1 = fma4v(o1, Lq[s], unpack_bf16x4(I[buf][r][1][xc]));
        o1 = fma4v(o1, Hq[s], unpack_bf16x4(I[buf][r][3][xc]));
      }
      const int jy = r0 + 2 * c + r;
      f32x4* po = ob + (size_t)(2 * jy) * (2 * N) + t;
      po[0] = o0;
      po[2 * N] = o1;
    }

    if (c < NC - 1) {
      // ---- Pass1: chunk c+1 (rows 2c+2, 2c+3) into other buffer ----
      // nA0/nA1 hold rows 2c+6, 2c+7 (loaded at chunk c-1 / prologue).
      p1(2 * c + 2, buf ^ 1, 0);
      w0[(2 * c + 2) & 3] = nA0;  // row 2c+6 -> slot (2c+2)&3 (mod-4 ok)
      w1[(2 * c + 2) & 3] = nB0;
      p1(2 * c + 3, buf ^ 1, 1);
      if (c < NC - 2) {
        w0[(2 * c + 3) & 3] = nA1;  // row 2c+7 -> slot (2c+3)&3
        w1[(2 * c + 3) & 3] = nB1;
        // Prefetch rows 2c+8, 2c+9 (consumed by chunk c+1's slides).
        ldrow(2 * c + 8, nA0, nB0);
        ldrow(2 * c + 9, nA1, nB1);
      }
      LGKM_BARRIER();
    }
  }
}

extern "C" void kernel_launch(void* const* d_in, const int* in_sizes, int n_in,
                              void* d_out, int out_size, void* d_ws,
                              size_t ws_size, hipStream_t stream) {
  const float* x = reinterpret_cast<const float*>(d_in[0]);
  float* out = reinterpret_cast<float*>(d_out);
  const int grid = 64 * (N / RJ);  // 1024 blocks
  idwt2_sep21_kernel<<<grid, 512, 0, stream>>>(x, out);
}

// Round 23
// 105.116 us; speedup vs baseline: 1.0340x; 1.0340x over previous
//
#include <hip/hip_runtime.h>

// IDWT2D db4, periodized. Input x: [64][256][256][16] f32 (cA|cH|cV|cD x 4ch),
// output: [64][512][512][4] f32.
//
// R22 = R14/R19 verbatim — the session best (106.9 / 107.1 us, reproduced).
// Final structure after 14 structural experiments:
// - Separable two-pass per block: 16 j-rows x full 256 cols, 512 threads.
// - Pass1 (y-filter): DENSE lane-contiguous global loads (thread t owns f4
//   cols t and t+512 of each input row); thread computes both-parity
//   partials with its subband-family weights and exchanges the
//   opposite-parity partial with lane t^1 via __shfl_xor -> one LDS f4
//   write per column per plane. 4-row register sliding window; each input
//   row loaded once per block; prefetch 1 row ahead.
// - LDS intermediate I[2][4][258] f32x4 (double-buffered; planes
//   0=lo*p0, 1=lo*p1, 2=hi*p0, 3=hi*p1; pad 256->258 for bank spread).
// - Pass2 (x-filter): thread = output column (dense coalesced f4 stores),
//   16 ds_read_b128 per row-step.
// - 1-row chunks, lgkm-only barrier (no vmcnt drain; prefetch stays in
//   flight), 4 blocks/CU (VGPR 64, LDS 33 KB).

#define N 256
#define RJ 16

typedef float f32x4 __attribute__((ext_vector_type(4)));

// lgkm-only barrier: LDS producer-consumer sync without vmcnt drain.
#define LGKM_BARRIER()                                   \
  do {                                                   \
    asm volatile("s_waitcnt lgkmcnt(0)" ::: "memory");   \
    __builtin_amdgcn_s_barrier();                        \
    asm volatile("" ::: "memory");                       \
  } while (0)

__device__ __forceinline__ f32x4 fma4v(const f32x4 acc, const float s,
                                       const f32x4 a) {
  const f32x4 sv = {s, s, s, s};
  return __builtin_elementwise_fma(a, sv, acc);
}

__device__ __forceinline__ f32x4 shflxor1(const f32x4 v) {
  f32x4 r;
  r.x = __shfl_xor(v.x, 1);
  r.y = __shfl_xor(v.y, 1);
  r.z = __shfl_xor(v.z, 1);
  r.w = __shfl_xor(v.w, 1);
  return r;
}

__global__ __launch_bounds__(512, 4) void idwt2_sep22_kernel(
    const float* __restrict__ x, float* __restrict__ out) {
  constexpr float LO[8] = {
      0.23037781330885523f,  0.7148465705525415f,  0.6308807679295904f,
      -0.02798376941698385f, -0.18703481171888114f, 0.030841381835986965f,
      0.032883011666982945f, -0.010597401784997278f};
  constexpr float HIW[8] = {
      -0.010597401784997278f, -0.032883011666982945f, 0.030841381835986965f,
      0.18703481171888114f,  -0.02798376941698385f,  -0.6308807679295904f,
      0.7148465705525415f,   -0.23037781330885523f};
  const float Lw[2][4] = {{LO[6], LO[4], LO[2], LO[0]},
                          {LO[7], LO[5], LO[3], LO[1]}};
  const float Hw[2][4] = {{HIW[6], HIW[4], HIW[2], HIW[0]},
                          {HIW[7], HIW[5], HIW[3], HIW[1]}};

  // [buf][plane][pixel] f32x4, pixel dim padded 256->258 for bank spread.
  __shared__ f32x4 I[2][4][258];

  const int t = threadIdx.x;
  const int bx = blockIdx.x;
  const int b = bx >> 4;           // 16 consecutive blocks per batch
  const int r0 = (bx & 15) * RJ;

  const f32x4* xb = reinterpret_cast<const f32x4*>(x) + (size_t)b * N * N * 4;
  f32x4* ob = reinterpret_cast<f32x4*>(out) + (size_t)b * (2 * N) * (2 * N);

  // ---- Pass1 identity: f4 index j = t (pixel p, subband-f4 f) + j+512 ----
  const int f = t & 3;
  const int p = t >> 2;  // 0..127; second column is p+128
  const bool fo = f & 1; // false: cA/cV (Lw family), true: cH/cD (Hw family)

  float w_own[4], w_opp[4];  // own-parity / opposite-parity weights
#pragma unroll
  for (int s = 0; s < 4; ++s) {
    w_own[s] = fo ? Hw[1][s] : Lw[0][s];
    w_opp[s] = fo ? Hw[0][s] : Lw[1][s];
  }

  f32x4 w0[4], w1[4], n0, n1;  // sliding windows for columns j=t, j=t+512
  auto ldrow = [&](int lr, f32x4& A, f32x4& B) {
    const int gr = (r0 + lr) & (N - 1);
    const f32x4* xrow = xb + (size_t)gr * (N * 4);
    A = xrow[t];
    B = xrow[t + 512];
  };

  // y-filter local j-row j into I[buf]; window slot (j+sy)&3 holds row j+sy.
  auto p1 = [&](int j, int buf) {
    f32x4 sAo = {0.f, 0.f, 0.f, 0.f}, sAx = {0.f, 0.f, 0.f, 0.f};
    f32x4 sBo = {0.f, 0.f, 0.f, 0.f}, sBx = {0.f, 0.f, 0.f, 0.f};
#pragma unroll
    for (int sy = 0; sy < 4; ++sy) {
      const f32x4 a = w0[(j + sy) & 3];
      const f32x4 bb = w1[(j + sy) & 3];
      sAo = fma4v(sAo, w_own[sy], a);
      sAx = fma4v(sAx, w_opp[sy], a);
      sBo = fma4v(sBo, w_own[sy], bb);
      sBx = fma4v(sBx, w_opp[sy], bb);
    }
    // Exchange opposite-parity partials with lane t^1, add to own.
    const f32x4 vA = sAo + shflxor1(sAx);
    const f32x4 vB = sBo + shflxor1(sBx);
    I[buf][f][p] = vA;
    I[buf][f][p + 128] = vB;
  };

  // Prologue: window rows 0..3, prefetch row 4; p1(0) -> I[0].
#pragma unroll
  for (int m = 0; m < 4; ++m) ldrow(m, w0[m], w1[m]);
  ldrow(4, n0, n1);
  p1(0, 0);
  w0[0] = n0;  // row 4 -> slot 0 (row 0 dead)
  w1[0] = n1;
  ldrow(5, n0, n1);
  LGKM_BARRIER();

  // ---- Pass2 identity: output column t (dense stores) ----
  const int jx = t >> 1;
  const int q = t & 1;
  float Lq[4], Hq[4];
#pragma unroll
  for (int s = 0; s < 4; ++s) {
    Lq[s] = q ? Lw[1][s] : Lw[0][s];
    Hq[s] = q ? Hw[1][s] : Hw[0][s];
  }

#pragma unroll
  for (int c = 0; c < RJ; ++c) {
    const int buf = c & 1;

    // ---- Pass2: x-filter j-row c from I[buf] ----
    // plane 0 = par0*lo, 1 = par1*lo, 2 = par0*hi, 3 = par1*hi
    f32x4 o0 = {0.f, 0.f, 0.f, 0.f};
    f32x4 o1 = {0.f, 0.f, 0.f, 0.f};
#pragma unroll
    for (int s = 0; s < 4; ++s) {
      const int xc = (jx + s) & (N - 1);
      o0 = fma4v(o0, Lq[s], I[buf][0][xc]);
      o0 = fma4v(o0, Hq[s], I[buf][2][xc]);
      o1 = fma4v(o1, Lq[s], I[buf][1][xc]);
      o1 = fma4v(o1, Hq[s], I[buf][3][xc]);
    }
    const int jy = r0 + c;
    f32x4* po = ob + (size_t)(2 * jy) * (2 * N) + t;
    po[0] = o0;
    po[2 * N] = o1;

    if (c < RJ - 1) {
      // ---- Pass1: j-row c+1 (uses window rows c+1..c+4) ----
      p1(c + 1, buf ^ 1);
      // Slide: row c+5 (prefetched, vmcnt-waited here) -> slot (c+1)&3;
      // issue prefetch of row c+6 (stays in flight across the barrier).
      if (c <= RJ - 3) {
        w0[(c + 1) & 3] = n0;
        w1[(c + 1) & 3] = n1;
      }
      if (c <= RJ - 4) ldrow(c + 6, n0, n1);
      LGKM_BARRIER();
    }
  }
}

extern "C" void kernel_launch(void* const* d_in, const int* in_sizes, int n_in,
                              void* d_out, int out_size, void* d_ws,
                              size_t ws_size, hipStream_t stream) {
  const float* x = reinterpret_cast<const float*>(d_in[0]);
  float* out = reinterpret_cast<float*>(d_out);
  const int grid = 64 * (N / RJ);  // 1024 blocks = 4 per CU
  idwt2_sep22_kernel<<<grid, 512, 0, stream>>>(x, out);
}